// Round 1
// baseline (163.762 us; speedup 1.0000x reference)
//
#include <hip/hip_runtime.h>

#define BLOCK 256
#define P 8          // points per thread in pass 1
#define MC 1024      // targets per LDS chunk

// Pass 1: for each point, min over one chunk of targets of
//   q = 0.5*||t||^2 - o·t      (d = ||o||^2 + 2q)
// then atomicMin the final d (uint bit pattern; d >= 0 so order matches).
__global__ __launch_bounds__(BLOCK) void cpl_pass1(
    const float* __restrict__ outputs, const float* __restrict__ targets,
    unsigned int* __restrict__ mins, int N) {
  __shared__ float4 tgt[MC];
  const int t = threadIdx.x;
  const int pb = blockIdx.x;   // point block
  const int cb = blockIdx.y;   // target chunk

  // Stage target chunk into LDS as {x, y, z, 0.5*||t||^2}
  for (int i = t; i < MC; i += BLOCK) {
    const int g = cb * MC + i;
    const float x = targets[3 * g + 0];
    const float y = targets[3 * g + 1];
    const float z = targets[3 * g + 2];
    tgt[i] = make_float4(x, y, z,
                         0.5f * __builtin_fmaf(x, x, __builtin_fmaf(y, y, z * z)));
  }
  __syncthreads();

  float ox[P], oy[P], oz[P], o2[P], mn[P];
  const int pbase = pb * (BLOCK * P);
#pragma unroll
  for (int k = 0; k < P; ++k) {
    const int p = pbase + k * BLOCK + t;
    const float x = outputs[3 * p + 0];
    const float y = outputs[3 * p + 1];
    const float z = outputs[3 * p + 2];
    ox[k] = x; oy[k] = y; oz[k] = z;
    o2[k] = __builtin_fmaf(x, x, __builtin_fmaf(y, y, z * z));
    mn[k] = 3.0e38f;
  }

#pragma unroll 4
  for (int j = 0; j < MC; ++j) {
    const float4 T = tgt[j];
#pragma unroll
    for (int k = 0; k < P; ++k) {
      float q = __builtin_fmaf(-ox[k], T.x, T.w);
      q = __builtin_fmaf(-oy[k], T.y, q);
      q = __builtin_fmaf(-oz[k], T.z, q);
      mn[k] = fminf(mn[k], q);
    }
  }

#pragma unroll
  for (int k = 0; k < P; ++k) {
    const int p = pbase + k * BLOCK + t;
    float d = __builtin_fmaf(2.0f, mn[k], o2[k]);
    d = fmaxf(d, 0.0f);  // guard tiny negative rounding so uint order == float order
    atomicMin(&mins[p], __float_as_uint(d));
  }
}

// Pass 2: deterministic fixed-tree partial sums of per-point min distances.
__global__ __launch_bounds__(BLOCK) void cpl_pass2(
    const float* __restrict__ mins, float* __restrict__ partial, int N) {
  __shared__ float red[BLOCK];
  const int t = threadIdx.x;
  float s = 0.0f;
  for (int i = blockIdx.x * BLOCK + t; i < N; i += gridDim.x * BLOCK)
    s += mins[i];
  red[t] = s;
  __syncthreads();
  for (int off = BLOCK / 2; off > 0; off >>= 1) {
    if (t < off) red[t] += red[t + off];
    __syncthreads();
  }
  if (t == 0) partial[blockIdx.x] = red[0];
}

// Pass 3: final reduce + mean.
__global__ __launch_bounds__(BLOCK) void cpl_pass3(
    const float* __restrict__ partial, float* __restrict__ out, int nb, float invN) {
  __shared__ float red[BLOCK];
  const int t = threadIdx.x;
  red[t] = (t < nb) ? partial[t] : 0.0f;
  __syncthreads();
  for (int off = BLOCK / 2; off > 0; off >>= 1) {
    if (t < off) red[t] += red[t + off];
    __syncthreads();
  }
  if (t == 0) out[0] = red[0] * invN;
}

extern "C" void kernel_launch(void* const* d_in, const int* in_sizes, int n_in,
                              void* d_out, int out_size, void* d_ws, size_t ws_size,
                              hipStream_t stream) {
  const float* outputs = (const float*)d_in[0];   // [N,3] f32
  const float* targets = (const float*)d_in[1];   // [M,3] f32
  float* out = (float*)d_out;                     // scalar f32

  const int N = in_sizes[0] / 3;  // 131072
  const int M = in_sizes[1] / 3;  // 16384

  unsigned int* mins = (unsigned int*)d_ws;                        // N uints
  float* partial = (float*)((char*)d_ws + (size_t)N * sizeof(float)); // 256 floats

  // Init per-point mins to 0x7F7F7F7F (= 3.39e38 as float) every call.
  hipMemsetAsync(d_ws, 0x7F, (size_t)N * sizeof(unsigned int), stream);

  dim3 g1(N / (BLOCK * P), M / MC);  // 64 x 16
  cpl_pass1<<<g1, BLOCK, 0, stream>>>(outputs, targets, mins, N);

  const int nb2 = 256;
  cpl_pass2<<<nb2, BLOCK, 0, stream>>>((const float*)mins, partial, N);
  cpl_pass3<<<1, BLOCK, 0, stream>>>(partial, out, nb2, 1.0f / (float)N);
}

// Round 2
// 158.291 us; speedup vs baseline: 1.0346x; 1.0346x over previous
//
#include <hip/hip_runtime.h>

#define BLOCK 256
#define P 8          // points per thread in pass 1
#define MC 512       // targets per LDS chunk (8 KB) -> grid 64x32 = 2048 blocks = 8/CU

// Pass 1: for each point, min over one chunk of targets of
//   q = 0.5*||t||^2 - o·t      (d = ||o||^2 + 2q)
// then atomicMin the final d (uint bit pattern; d >= 0 so order matches).
__global__ __launch_bounds__(BLOCK) void cpl_pass1(
    const float* __restrict__ outputs, const float* __restrict__ targets,
    unsigned int* __restrict__ mins, int N) {
  __shared__ float4 tgt[MC];
  const int t = threadIdx.x;
  const int pb = blockIdx.x;   // point block
  const int cb = blockIdx.y;   // target chunk

  // Stage target chunk into LDS as {x, y, z, 0.5*||t||^2}
  for (int i = t; i < MC; i += BLOCK) {
    const int g = cb * MC + i;
    const float x = targets[3 * g + 0];
    const float y = targets[3 * g + 1];
    const float z = targets[3 * g + 2];
    tgt[i] = make_float4(x, y, z,
                         0.5f * __builtin_fmaf(x, x, __builtin_fmaf(y, y, z * z)));
  }
  __syncthreads();

  float ox[P], oy[P], oz[P], o2[P], mn[P];
  const int pbase = pb * (BLOCK * P);
#pragma unroll
  for (int k = 0; k < P; ++k) {
    const int p = pbase + k * BLOCK + t;
    const float x = outputs[3 * p + 0];
    const float y = outputs[3 * p + 1];
    const float z = outputs[3 * p + 2];
    ox[k] = x; oy[k] = y; oz[k] = z;
    o2[k] = __builtin_fmaf(x, x, __builtin_fmaf(y, y, z * z));
    mn[k] = 3.0e38f;
  }

#pragma unroll 4
  for (int j = 0; j < MC; ++j) {
    const float4 T = tgt[j];
#pragma unroll
    for (int k = 0; k < P; ++k) {
      float q = __builtin_fmaf(-ox[k], T.x, T.w);
      q = __builtin_fmaf(-oy[k], T.y, q);
      q = __builtin_fmaf(-oz[k], T.z, q);
      mn[k] = fminf(mn[k], q);
    }
  }

#pragma unroll
  for (int k = 0; k < P; ++k) {
    const int p = pbase + k * BLOCK + t;
    float d = __builtin_fmaf(2.0f, mn[k], o2[k]);
    d = fmaxf(d, 0.0f);  // guard tiny negative rounding so uint order == float order
    atomicMin(&mins[p], __float_as_uint(d));
  }
}

// Pass 2: deterministic fixed-tree partial sums of per-point min distances.
__global__ __launch_bounds__(BLOCK) void cpl_pass2(
    const float* __restrict__ mins, float* __restrict__ partial, int N) {
  __shared__ float red[BLOCK];
  const int t = threadIdx.x;
  float s = 0.0f;
  for (int i = blockIdx.x * BLOCK + t; i < N; i += gridDim.x * BLOCK)
    s += mins[i];
  red[t] = s;
  __syncthreads();
  for (int off = BLOCK / 2; off > 0; off >>= 1) {
    if (t < off) red[t] += red[t + off];
    __syncthreads();
  }
  if (t == 0) partial[blockIdx.x] = red[0];
}

// Pass 3: final reduce + mean.
__global__ __launch_bounds__(BLOCK) void cpl_pass3(
    const float* __restrict__ partial, float* __restrict__ out, int nb, float invN) {
  __shared__ float red[BLOCK];
  const int t = threadIdx.x;
  red[t] = (t < nb) ? partial[t] : 0.0f;
  __syncthreads();
  for (int off = BLOCK / 2; off > 0; off >>= 1) {
    if (t < off) red[t] += red[t + off];
    __syncthreads();
  }
  if (t == 0) out[0] = red[0] * invN;
}

extern "C" void kernel_launch(void* const* d_in, const int* in_sizes, int n_in,
                              void* d_out, int out_size, void* d_ws, size_t ws_size,
                              hipStream_t stream) {
  const float* outputs = (const float*)d_in[0];   // [N,3] f32
  const float* targets = (const float*)d_in[1];   // [M,3] f32
  float* out = (float*)d_out;                     // scalar f32

  const int N = in_sizes[0] / 3;  // 131072
  const int M = in_sizes[1] / 3;  // 16384

  unsigned int* mins = (unsigned int*)d_ws;                           // N uints
  float* partial = (float*)((char*)d_ws + (size_t)N * sizeof(float)); // 256 floats

  // Init per-point mins to 0x7F7F7F7F (= 3.39e38 as float) every call.
  hipMemsetAsync(d_ws, 0x7F, (size_t)N * sizeof(unsigned int), stream);

  dim3 g1(N / (BLOCK * P), M / MC);  // 64 x 32 = 2048 blocks = 8/CU
  cpl_pass1<<<g1, BLOCK, 0, stream>>>(outputs, targets, mins, N);

  const int nb2 = 256;
  cpl_pass2<<<nb2, BLOCK, 0, stream>>>((const float*)mins, partial, N);
  cpl_pass3<<<1, BLOCK, 0, stream>>>(partial, out, nb2, 1.0f / (float)N);
}

// Round 3
// 107.113 us; speedup vs baseline: 1.5289x; 1.4778x over previous
//
#include <hip/hip_runtime.h>
#include <stdint.h>

typedef __attribute__((ext_vector_type(8))) _Float16 half8;
typedef __attribute__((ext_vector_type(16))) float f32x16;

#define NPTS 131072
#define NTGT 16384
#define NJT (NTGT / 32)          // 512 j-tiles of 32 targets
#define STAGE_JT 16              // j-tiles per LDS stage
#define NSTAGE (NJT / STAGE_JT)  // 32
#define STAGE_BYTES (STAGE_JT * 64 * 16)  // 16 KB

// Split scale: lifts f16 low-order split terms out of denormal range. Exact pow2.
#define SPLIT_S 512.0f
#define INV_S (1.0f / 512.0f)

// ---------- prep: pack each target into two 16B B-fragments --------------
// Slot pairing (k): 0:2oxh*-txh 1:2oxl*-txh 2:2oxh*-txl 3..5:y 6..8:z
//                   9:o2h*1 10:o2l*1 11:1*t2h 12:1*t2l 13-15:zero
// Storage order is MFMA-lane order: bfrag[jt*64 + (lane&31) + (lane>>5)*32]
__global__ __launch_bounds__(256) void cpl_prep(const float* __restrict__ targets,
                                                half8* __restrict__ bfrag) {
  const int j = blockIdx.x * 256 + threadIdx.x;
  if (j >= NTGT) return;
  const float tx = targets[3 * j + 0], ty = targets[3 * j + 1], tz = targets[3 * j + 2];
  const float t2 = fmaf(tx, tx, fmaf(ty, ty, tz * tz));
  const _Float16 txh = (_Float16)tx; const float txl = tx - (float)txh;
  const _Float16 tyh = (_Float16)ty; const float tyl = ty - (float)tyh;
  const _Float16 tzh = (_Float16)tz; const float tzl = tz - (float)tzh;
  const _Float16 t2h = (_Float16)t2; const float t2l = t2 - (float)t2h;
  half8 blo, bhi;
  blo[0] = -txh; blo[1] = (_Float16)(-(float)txh * INV_S); blo[2] = (_Float16)(-txl * SPLIT_S);
  blo[3] = -tyh; blo[4] = (_Float16)(-(float)tyh * INV_S); blo[5] = (_Float16)(-tyl * SPLIT_S);
  blo[6] = -tzh; blo[7] = (_Float16)(-(float)tzh * INV_S);
  bhi[0] = (_Float16)(-tzl * SPLIT_S);
  bhi[1] = (_Float16)1.0f; bhi[2] = (_Float16)INV_S;
  bhi[3] = t2h;            bhi[4] = (_Float16)(t2l * SPLIT_S);
  bhi[5] = (_Float16)0.0f; bhi[6] = (_Float16)0.0f; bhi[7] = (_Float16)0.0f;
  const int jt = j >> 5, jj = j & 31;
  bfrag[jt * 64 + jj] = blo;
  bfrag[jt * 64 + 32 + jj] = bhi;
}

// ---------- A-fragment builder (per lane, per point) ----------------------
__device__ __forceinline__ half8 make_afrag(const float* __restrict__ o, int p, int hi) {
  const float sx = 2.0f * o[3 * p + 0], sy = 2.0f * o[3 * p + 1], sz = 2.0f * o[3 * p + 2];
  const float o2 = 0.25f * fmaf(sx, sx, fmaf(sy, sy, sz * sz));  // x^2+y^2+z^2
  const _Float16 xh = (_Float16)sx; const float xl = sx - (float)xh;
  const _Float16 yh = (_Float16)sy; const float yl = sy - (float)yh;
  const _Float16 zh = (_Float16)sz; const float zl = sz - (float)zh;
  const _Float16 qh = (_Float16)o2; const float ql = o2 - (float)qh;
  half8 lo, hi8;
  lo[0] = xh; lo[1] = (_Float16)(xl * SPLIT_S); lo[2] = (_Float16)((float)xh * INV_S);
  lo[3] = yh; lo[4] = (_Float16)(yl * SPLIT_S); lo[5] = (_Float16)((float)yh * INV_S);
  lo[6] = zh; lo[7] = (_Float16)(zl * SPLIT_S);
  hi8[0] = (_Float16)((float)zh * INV_S);
  hi8[1] = qh;             hi8[2] = (_Float16)(ql * SPLIT_S);
  hi8[3] = (_Float16)1.0f; hi8[4] = (_Float16)INV_S;
  hi8[5] = (_Float16)0.0f; hi8[6] = (_Float16)0.0f; hi8[7] = (_Float16)0.0f;
  return hi ? hi8 : lo;
}

__device__ __forceinline__ void gload16(const void* g, void* l) {
  __builtin_amdgcn_global_load_lds(
      (const __attribute__((address_space(1))) uint32_t*)g,
      (__attribute__((address_space(3))) uint32_t*)l, 16, 0, 0);
}

// ---------- main: each wave owns 2 point-tiles (64 points), loops all targets
__global__ __launch_bounds__(256) void cpl_main(const float* __restrict__ outputs,
                                                const char* __restrict__ bfrag_b,
                                                float* __restrict__ partial) {
  __shared__ __align__(16) char smem[2][STAGE_BYTES];
  const int tid = threadIdx.x;
  const int lane = tid & 63;
  const int w = tid >> 6;           // wave in block (0..3)
  const int hi = lane >> 5;
  const int gw = blockIdx.x * 4 + w;  // global wave id (0..2047)

  const int prow = lane & 31;
  const half8 a0 = make_afrag(outputs, gw * 64 + prow, hi);
  const half8 a1 = make_afrag(outputs, gw * 64 + 32 + prow, hi);

  f32x16 mn0, mn1, zed;
#pragma unroll
  for (int r = 0; r < 16; ++r) { zed[r] = 0.0f; mn0[r] = 3.0e38f; mn1[r] = 3.0e38f; }

  auto stage = [&](int s, int b) {
    const char* gbase = bfrag_b + (size_t)s * STAGE_BYTES + w * 4096 + lane * 16;
    char* lbase = &smem[b][w * 4096];
#pragma unroll
    for (int c = 0; c < 4; ++c) gload16(gbase + c * 1024, lbase + c * 1024);
  };

  stage(0, 0);
  int buf = 0;
  for (int s = 0; s < NSTAGE; ++s) {
    __syncthreads();  // drains current stage's loads; protects buffer reuse
    if (s + 1 < NSTAGE) stage(s + 1, buf ^ 1);  // async prefetch under compute
#pragma unroll
    for (int jp = 0; jp < STAGE_JT / 2; ++jp) {
      const half8 b0 = *(const half8*)&smem[buf][(2 * jp + 0) * 1024 + lane * 16];
      const half8 b1 = *(const half8*)&smem[buf][(2 * jp + 1) * 1024 + lane * 16];
      f32x16 p0 = __builtin_amdgcn_mfma_f32_32x32x16_f16(a0, b0, zed, 0, 0, 0);
      f32x16 p1 = __builtin_amdgcn_mfma_f32_32x32x16_f16(a0, b1, zed, 0, 0, 0);
      f32x16 q0 = __builtin_amdgcn_mfma_f32_32x32x16_f16(a1, b0, zed, 0, 0, 0);
      f32x16 q1 = __builtin_amdgcn_mfma_f32_32x32x16_f16(a1, b1, zed, 0, 0, 0);
#pragma unroll
      for (int r = 0; r < 16; ++r) mn0[r] = fminf(fminf(p0[r], p1[r]), mn0[r]);
#pragma unroll
      for (int r = 0; r < 16; ++r) mn1[r] = fminf(fminf(q0[r], q1[r]), mn1[r]);
    }
    buf ^= 1;
  }

  // Min across 32 columns (targets) = butterfly within each 32-lane half.
#pragma unroll
  for (int r = 0; r < 16; ++r) {
    float v0 = mn0[r], v1 = mn1[r];
#pragma unroll
    for (int m = 1; m <= 16; m <<= 1) {
      v0 = fminf(v0, __shfl_xor(v0, m, 64));
      v1 = fminf(v1, __shfl_xor(v1, m, 64));
    }
    mn0[r] = v0; mn1[r] = v1;
  }
  // Sum this wave's 64 per-point mins (16 regs x 2 halves x 2 itiles).
  float ssum = 0.0f;
#pragma unroll
  for (int r = 0; r < 16; ++r) ssum += mn0[r] + mn1[r];
  ssum += __shfl_xor(ssum, 32, 64);
  if (lane == 0) partial[gw] = ssum;
}

// ---------- final deterministic reduce ------------------------------------
__global__ __launch_bounds__(256) void cpl_reduce(const float* __restrict__ partial,
                                                  float* __restrict__ out) {
  __shared__ float red[256];
  const int t = threadIdx.x;
  float s = 0.0f;
#pragma unroll
  for (int i = 0; i < 8; ++i) s += partial[t + 256 * i];  // 2048 partials
  red[t] = s;
  __syncthreads();
  for (int off = 128; off > 0; off >>= 1) {
    if (t < off) red[t] += red[t + off];
    __syncthreads();
  }
  if (t == 0) out[0] = red[0] * (1.0f / (float)NPTS);
}

extern "C" void kernel_launch(void* const* d_in, const int* in_sizes, int n_in,
                              void* d_out, int out_size, void* d_ws, size_t ws_size,
                              hipStream_t stream) {
  const float* outputs = (const float*)d_in[0];  // [131072,3] f32
  const float* targets = (const float*)d_in[1];  // [16384,3] f32
  float* out = (float*)d_out;

  half8* bfrag = (half8*)d_ws;                                  // 512 KB
  float* partial = (float*)((char*)d_ws + (size_t)512 * 1024);  // 2048 floats

  cpl_prep<<<NTGT / 256, 256, 0, stream>>>(targets, bfrag);
  cpl_main<<<NPTS / 256, 256, 0, stream>>>(outputs, (const char*)d_ws, partial);
  cpl_reduce<<<1, 256, 0, stream>>>(partial, out);
}